// Round 12
// baseline (65.208 us; speedup 1.0000x reference)
//
#include <hip/hip_runtime.h>

typedef unsigned short u16;
typedef unsigned int u32;
typedef __bf16 bf16x8 __attribute__((ext_vector_type(8)));
typedef float f32x4 __attribute__((ext_vector_type(4)));

#define GLD_LDS(gptr, lptr) \
  __builtin_amdgcn_global_load_lds((const __attribute__((address_space(1))) void*)(gptr), \
                                   (__attribute__((address_space(3))) void*)(lptr), 16, 0, 0)

__device__ __forceinline__ u16 f2b(float f) {
  union { __bf16 h; u16 u; } v; v.h = (__bf16)f; return v.u;
}
__device__ __forceinline__ float elu1(float v) {
  return v > 0.f ? v : (__expf(v) - 1.f);
}

// ---------------- 64x64 transpose-convert tile (f32 [R][C] -> bf16 [C][R]) ----------------
__device__ void transpose_tile(float (*tbuf)[65], const float* __restrict__ src,
                               u16* __restrict__ dst, int R, int C, int tr, int tc,
                               size_t zoff) {
  const int tid = threadIdx.x;
  const float* sp = src + zoff + (size_t)(tr * 64) * C + tc * 64;
#pragma unroll
  for (int i = 0; i < 4; i++) {
    const int rr = (tid >> 4) + i * 16, f = tid & 15;
    float4 v = *reinterpret_cast<const float4*>(sp + (size_t)rr * C + f * 4);
    tbuf[rr][f * 4 + 0] = v.x; tbuf[rr][f * 4 + 1] = v.y;
    tbuf[rr][f * 4 + 2] = v.z; tbuf[rr][f * 4 + 3] = v.w;
  }
  __syncthreads();
  u16* dp = dst + zoff + (size_t)(tc * 64) * R + tr * 64;
#pragma unroll
  for (int i = 0; i < 4; i++) {
    const int u = tid + i * 256;
    const int c = u >> 4, rq = u & 15;
    ushort4 w;
    w.x = f2b(tbuf[rq * 4 + 0][c]); w.y = f2b(tbuf[rq * 4 + 1][c]);
    w.z = f2b(tbuf[rq * 4 + 2][c]); w.w = f2b(tbuf[rq * 4 + 3][c]);
    *reinterpret_cast<ushort4*>(dp + (size_t)c * R + rq * 4) = w;
  }
}

// ---------------- routing, stage 1: per-chunk histogram ----------------
__device__ void hist_body(int rb, const int* __restrict__ cat, int* __restrict__ cnts) {
  __shared__ int c8[8];
  const int tid = threadIdx.x;
  if (tid < 8) c8[tid] = 0;
  __syncthreads();
  if (tid < 128) atomicAdd(&c8[cat[rb * 128 + tid]], 1);
  __syncthreads();
  if (tid < 8) cnts[rb * 8 + tid] = c8[tid];
}

// ---------------- routing, stage 2: independent prefix + scatter ----------------
__device__ void scatter_body(int rb, const int* __restrict__ cat,
                             const int* __restrict__ cnts,
                             int* __restrict__ list, int* __restrict__ off) {
  __shared__ int lc[512];
  __shared__ int lcur[8];
  __shared__ int starts[8];
  const int tid = threadIdx.x;
  lc[tid] = cnts[tid];
  lc[tid + 256] = cnts[tid + 256];
  if (tid < 8) lcur[tid] = 0;
  __syncthreads();
  if (tid < 8) {
    const int c = tid;
    int base = 0;
    for (int cc = 0; cc < c; cc++) {
      int s = 0;
      for (int b = 0; b < 64; b++) s += lc[b * 8 + cc];
      base += s;
    }
    int pre = 0;
    for (int b = 0; b < rb; b++) pre += lc[b * 8 + c];
    starts[c] = base + pre;
    if (rb == 0) {
      off[c] = base;
      if (c == 7) {
        int s = 0;
        for (int b = 0; b < 64; b++) s += lc[b * 8 + 7];
        off[8] = base + s;
      }
    }
  }
  __syncthreads();
  if (tid < 128) {
    const int idx = rb * 128 + tid;
    const int c = cat[idx];
    const int r = atomicAdd(&lcur[c], 1);
    list[starts[c] + r] = idx;
  }
}

// ---------------- small front kernel: W_in transpose + routing histogram ----------------
__global__ __launch_bounds__(256) void wsmall(const float* __restrict__ W_in,
                                              const int* __restrict__ cat,
                                              u16* __restrict__ o0, int* __restrict__ cnts) {
  __shared__ float tbuf[64][65];
  if (blockIdx.x >= 128) { hist_body(blockIdx.x - 128, cat, cnts); return; }
  transpose_tile(tbuf, W_in, o0, 512, 1024, blockIdx.x >> 4, blockIdx.x & 15, 0);
}

// ---------------- unified GEMM + T1 swizzle; L2/L3: 3-buf distance-2 counted-vmcnt --------
// L1: R3 loop (A = x f32 reg-staged), riders y==8 scatter, y==9..16 W1, y==17 W2.
// L2: gathered rows, single-barrier pipelined loop, bf16 out + ELU.
// L3: compact rows, same pipelined loop, f32 out scattered.

template<int LAYER, int BN, int K, int N>
__global__ __launch_bounds__(256, 4) void gemm_t(
    const float* __restrict__ Xf, const u16* __restrict__ A,
    const u16* __restrict__ Bw, const float* __restrict__ bias,
    const int* __restrict__ list, const int* __restrict__ off,
    u16* __restrict__ outb, float* __restrict__ outf,
    const int* __restrict__ cat, const int* __restrict__ cnts,
    int* __restrict__ wlist, int* __restrict__ woff,
    const float* __restrict__ Wc1, const float* __restrict__ Wc2,
    u16* __restrict__ o1, u16* __restrict__ o2) {
  constexpr int NBUF = (LAYER == 1) ? 2 : 3;
  struct GBuf { alignas(16) u16 As[NBUF][2048]; alignas(16) u16 Bs[NBUF][BN * 32]; };
  __shared__ union SM { GBuf g; float tbuf[64][65]; } sm;

  const int tid = threadIdx.x;

  if constexpr (LAYER == 1) {
    if (blockIdx.y == 8) {
      if (blockIdx.x < 64) scatter_body(blockIdx.x, cat, cnts, wlist, woff);
      return;
    }
    if (blockIdx.y >= 9) {
      if (blockIdx.y <= 16) {
        const int t = (blockIdx.y - 9) * 128 + blockIdx.x;
        const int z = t >> 7, rem = t & 127;
        transpose_tile(sm.tbuf, Wc1, o1, 1024, 512, rem >> 3, rem & 7,
                       (size_t)z * 1024 * 512);
      } else if (blockIdx.x < 64) {
        const int t = blockIdx.x, z = t >> 3;
        transpose_tile(sm.tbuf, Wc2, o2, 512, 64, t & 7, 0, (size_t)z * 512 * 64);
      }
      return;
    }
  }

  // ---- T1: XCD-chunked bijective block swizzle ----
  int tidx, col0;
  if constexpr (LAYER == 1) {
    const int orig = blockIdx.y * 128 + blockIdx.x;
    const int work = (orig & 7) * 128 + (orig >> 3);
    tidx = work >> 3;
    col0 = (work & 7) * BN;
  } else if constexpr (LAYER == 2) {
    const int orig = blockIdx.y * 136 + blockIdx.x;
    const int work = (orig & 7) * 68 + (orig >> 3);
    tidx = work >> 2;
    col0 = (work & 3) * BN;
  } else {
    const int orig = blockIdx.x;
    const int work = (orig & 7) * 17 + (orig >> 3);
    tidx = work;
    col0 = 0;
  }

  const int wave = tid >> 6, lane = tid & 63;

  int e = 0, start = 0, cnt = 0, rowbase;
  if constexpr (LAYER == 1) {
    rowbase = tidx * 64;
  } else {
    int t = tidx;
    int found = -1;
    for (e = 0; e < 8; e++) {
      int tiles = (off[e + 1] - off[e] + 63) >> 6;
      if (t < tiles) { found = e; break; }
      t -= tiles;
    }
    if (found < 0) return;
    start = off[e];
    cnt = off[e + 1] - start;
    rowbase = t * 64;
  }

  const int srow = tid >> 2, skc = tid & 3;
  const int kxs = (skc ^ (srow & 3)) * 8;

  const float* ax = nullptr;
  const u16* a_src = nullptr;
  if constexpr (LAYER == 1) {
    ax = Xf + (size_t)(rowbase + srow) * K + kxs;
  } else if constexpr (LAYER == 2) {
    int gr = list[start + min(rowbase + srow, cnt - 1)];
    a_src = A + (size_t)gr * K + kxs;
  } else {
    a_src = A + (size_t)(start + min(rowbase + srow, cnt - 1)) * K + kxs;
  }
  const u16* Bbase = Bw + (LAYER == 1 ? (size_t)0 : (size_t)e * N * K);
  const u16* b_src0 = Bbase + (size_t)(col0 + srow) * K + kxs;
  const u16* b_src1 = Bbase + (size_t)(col0 + 64 + srow) * K + kxs;

  const int wbase = wave * 512;

  constexpr int NR = BN / 32;
  const int wy = wave & 1, wx = wave >> 1;
  const int fr = lane & 15, kg = lane >> 4;
  const int kx = (kg ^ (fr & 3)) * 8;
  const int ar0 = (wy * 32 + fr) * 32 + kx;
  const int br0 = (wx * (BN / 2) + fr) * 32 + kx;

  f32x4 acc[2][NR] = {};

  float4 va0, va1;                          // L1 in-flight A (f32)
  auto LOAD_A1 = [&](int t) {
    va0 = *reinterpret_cast<const float4*>(ax + t * 32);
    va1 = *reinterpret_cast<const float4*>(ax + t * 32 + 4);
  };
  auto WRITE_A1 = [&](int buf) {
    uint4 w;
    w.x = (u32)f2b(va0.x) | ((u32)f2b(va0.y) << 16);
    w.y = (u32)f2b(va0.z) | ((u32)f2b(va0.w) << 16);
    w.z = (u32)f2b(va1.x) | ((u32)f2b(va1.y) << 16);
    w.w = (u32)f2b(va1.z) | ((u32)f2b(va1.w) << 16);
    *reinterpret_cast<uint4*>(&sm.g.As[buf][srow * 32 + skc * 8]) = w;
  };
  auto STAGE = [&](int t, int buf) {
    const int kt = t * 32;
    GLD_LDS(a_src + kt, &sm.g.As[buf][wbase]);
    GLD_LDS(b_src0 + kt, &sm.g.Bs[buf][wbase]);
    if constexpr (BN == 128) GLD_LDS(b_src1 + kt, &sm.g.Bs[buf][2048 + wbase]);
  };
  auto COMPUTE = [&](int buf) {
    bf16x8 af[2], bfv[NR];
#pragma unroll
    for (int m = 0; m < 2; m++) af[m] = *(const bf16x8*)&sm.g.As[buf][ar0 + m * 16 * 32];
#pragma unroll
    for (int n = 0; n < NR; n++) bfv[n] = *(const bf16x8*)&sm.g.Bs[buf][br0 + n * 16 * 32];
#pragma unroll
    for (int m = 0; m < 2; m++)
#pragma unroll
      for (int n = 0; n < NR; n++)
        acc[m][n] = __builtin_amdgcn_mfma_f32_16x16x32_bf16(af[m], bfv[n], acc[m][n], 0, 0, 0);
  };

  constexpr int NK = K / 32;

  if constexpr (LAYER == 1) {
    // R3-proven depth-1 loop (reg-staged A would pollute vmcnt counting)
    LOAD_A1(0);
    GLD_LDS(b_src0, &sm.g.Bs[0][wbase]);
    if constexpr (BN == 128) GLD_LDS(b_src1, &sm.g.Bs[0][2048 + wbase]);
    WRITE_A1(0);
    __syncthreads();
    for (int it = 0; it < NK; ++it) {
      const int cur = it & 1;
      const int nxt = cur ^ 1;
      if (it + 1 < NK) {
        const int kt = (it + 1) * 32;
        LOAD_A1(it + 1);
        GLD_LDS(b_src0 + kt, &sm.g.Bs[nxt][wbase]);
        if constexpr (BN == 128) GLD_LDS(b_src1 + kt, &sm.g.Bs[nxt][2048 + wbase]);
      }
      COMPUTE(cur);
      if (it + 1 < NK) WRITE_A1(nxt);
      __syncthreads();
    }
  } else {
    // T4: 3-buffer, distance-2, counted vmcnt, ONE barrier per iter.
    // Hazards: RAW — each wave's vmcnt(S) before barrier => STAGE(t) visible after it.
    //          WAR — STAGE(t+2) (overwrites COMPUTE(t-1)'s buf) issued only after the
    //                barrier proving all waves finished COMPUTE(t-1).
    constexpr int S = (BN == 128) ? 3 : 2;   // GLD_LDS per wave per stage
    STAGE(0, 0);
    STAGE(1, 1);
    int b0 = 0, b1 = 1, b2 = 2;
    for (int t = 0; t < NK - 1; ++t) {
      asm volatile("s_waitcnt vmcnt(%0)" :: "n"(S) : "memory");  // STAGE(t) done, t+1 in flight
      __builtin_amdgcn_s_barrier();
      if (t + 2 < NK) STAGE(t + 2, b2);
      COMPUTE(b0);
      const int tmp = b0; b0 = b1; b1 = b2; b2 = tmp;
    }
    asm volatile("s_waitcnt vmcnt(0)" ::: "memory");
    __builtin_amdgcn_s_barrier();
    COMPUTE(b0);
  }

#pragma unroll
  for (int n = 0; n < NR; n++) {
    const int col = col0 + wx * (BN / 2) + n * 16 + fr;
    const float bc = bias[(LAYER == 1 ? 0 : e * N) + col];
#pragma unroll
    for (int m = 0; m < 2; m++) {
      const int rloc = wy * 32 + m * 16 + kg * 4;
#pragma unroll
      for (int j = 0; j < 4; j++) {
        const float v = acc[m][n][j] + bc;
        if constexpr (LAYER == 1) {
          outb[(size_t)(rowbase + rloc + j) * N + col] = f2b(elu1(v));
        } else if constexpr (LAYER == 2) {
          const int slot = rowbase + rloc + j;
          if (slot < cnt) outb[(size_t)(start + slot) * N + col] = f2b(elu1(v));
        } else {
          const int slot = rowbase + rloc + j;
          if (slot < cnt) outf[(size_t)list[start + slot] * N + col] = v;
        }
      }
    }
  }
}

// ---------------- launch ----------------

extern "C" void kernel_launch(void* const* d_in, const int* in_sizes, int n_in,
                              void* d_out, int out_size, void* d_ws, size_t ws_size,
                              hipStream_t stream) {
  const float* x    = (const float*)d_in[0];
  const int*   cat  = (const int*)d_in[1];
  const float* W_in = (const float*)d_in[2];
  const float* b_in = (const float*)d_in[3];
  const float* W1   = (const float*)d_in[4];
  const float* b1   = (const float*)d_in[5];
  const float* W2   = (const float*)d_in[6];
  const float* b2   = (const float*)d_in[7];
  float* out = (float*)d_out;

  char* p = (char*)d_ws;
  u16* midb = (u16*)p; p += (size_t)8192 * 1024 * 2;
  u16* hb   = (u16*)p; p += (size_t)8192 * 512 * 2;
  u16* wtin = (u16*)p; p += (size_t)1024 * 512 * 2;
  u16* w1t  = (u16*)p; p += (size_t)8 * 512 * 1024 * 2;
  u16* w2t  = (u16*)p; p += (size_t)8 * 64 * 512 * 2;
  int* list = (int*)p; p += (size_t)8192 * 4;
  int* off  = (int*)p; p += 64;
  int* cnts = (int*)p; p += 64 * 8 * 4;

  // D1: W_in transpose + routing histogram
  wsmall<<<192, 256, 0, stream>>>(W_in, cat, wtin, cnts);

  // D2: L1 gemm (x as f32) + scatter (y==8) + W1/W2 converts (y>=9)
  gemm_t<1, 128, 512, 1024><<<dim3(128, 18), 256, 0, stream>>>(
      x, nullptr, wtin, b_in, nullptr, nullptr, midb, nullptr,
      cat, cnts, list, off, W1, W2, w1t, w2t);

  // D3: L2 grouped  [cnt_e,1024] @ [1024,512] -> hb (compact)
  gemm_t<2, 128, 1024, 512><<<dim3(136, 4), 256, 0, stream>>>(
      nullptr, midb, w1t, b1, list, off, hb, nullptr,
      nullptr, nullptr, nullptr, nullptr, nullptr, nullptr, nullptr, nullptr);

  // D4: L3 grouped  [cnt_e,512] @ [512,64] -> out (scattered)
  gemm_t<3, 64, 512, 64><<<dim3(136, 1), 256, 0, stream>>>(
      nullptr, hb, w2t, b2, list, off, nullptr, out,
      nullptr, nullptr, nullptr, nullptr, nullptr, nullptr, nullptr, nullptr);
}

// Round 13
// 59.733 us; speedup vs baseline: 1.0917x; 1.0917x over previous
//
#include <hip/hip_runtime.h>

typedef unsigned short u16;
typedef unsigned int u32;
typedef __bf16 bf16x8 __attribute__((ext_vector_type(8)));
typedef float f32x4 __attribute__((ext_vector_type(4)));

#define GLD_LDS(gptr, lptr) \
  __builtin_amdgcn_global_load_lds((const __attribute__((address_space(1))) void*)(gptr), \
                                   (__attribute__((address_space(3))) void*)(lptr), 16, 0, 0)

__device__ __forceinline__ u16 f2b(float f) {
  union { __bf16 h; u16 u; } v; v.h = (__bf16)f; return v.u;
}
__device__ __forceinline__ float elu1(float v) {
  return v > 0.f ? v : (__expf(v) - 1.f);
}

// ---------------- 64x64 transpose-convert tile (f32 [R][C] -> bf16 [C][R]) ----------------
__device__ void transpose_tile(float (*tbuf)[65], const float* __restrict__ src,
                               u16* __restrict__ dst, int R, int C, int tr, int tc,
                               size_t zoff) {
  const int tid = threadIdx.x;
  const float* sp = src + zoff + (size_t)(tr * 64) * C + tc * 64;
#pragma unroll
  for (int i = 0; i < 4; i++) {
    const int rr = (tid >> 4) + i * 16, f = tid & 15;
    float4 v = *reinterpret_cast<const float4*>(sp + (size_t)rr * C + f * 4);
    tbuf[rr][f * 4 + 0] = v.x; tbuf[rr][f * 4 + 1] = v.y;
    tbuf[rr][f * 4 + 2] = v.z; tbuf[rr][f * 4 + 3] = v.w;
  }
  __syncthreads();
  u16* dp = dst + zoff + (size_t)(tc * 64) * R + tr * 64;
#pragma unroll
  for (int i = 0; i < 4; i++) {
    const int u = tid + i * 256;
    const int c = u >> 4, rq = u & 15;
    ushort4 w;
    w.x = f2b(tbuf[rq * 4 + 0][c]); w.y = f2b(tbuf[rq * 4 + 1][c]);
    w.z = f2b(tbuf[rq * 4 + 2][c]); w.w = f2b(tbuf[rq * 4 + 3][c]);
    *reinterpret_cast<ushort4*>(dp + (size_t)c * R + rq * 4) = w;
  }
}

// ---------------- routing, stage 1: per-chunk histogram ----------------
__device__ void hist_body(int rb, const int* __restrict__ cat, int* __restrict__ cnts) {
  __shared__ int c8[8];
  const int tid = threadIdx.x;
  if (tid < 8) c8[tid] = 0;
  __syncthreads();
  if (tid < 128) atomicAdd(&c8[cat[rb * 128 + tid]], 1);
  __syncthreads();
  if (tid < 8) cnts[rb * 8 + tid] = c8[tid];
}

// ---------------- routing, stage 2: independent prefix + scatter ----------------
__device__ void scatter_body(int rb, const int* __restrict__ cat,
                             const int* __restrict__ cnts,
                             int* __restrict__ list, int* __restrict__ off) {
  __shared__ int lc[512];
  __shared__ int lcur[8];
  __shared__ int starts[8];
  const int tid = threadIdx.x;
  lc[tid] = cnts[tid];
  lc[tid + 256] = cnts[tid + 256];
  if (tid < 8) lcur[tid] = 0;
  __syncthreads();
  if (tid < 8) {
    const int c = tid;
    int base = 0;
    for (int cc = 0; cc < c; cc++) {
      int s = 0;
      for (int b = 0; b < 64; b++) s += lc[b * 8 + cc];
      base += s;
    }
    int pre = 0;
    for (int b = 0; b < rb; b++) pre += lc[b * 8 + c];
    starts[c] = base + pre;
    if (rb == 0) {
      off[c] = base;
      if (c == 7) {
        int s = 0;
        for (int b = 0; b < 64; b++) s += lc[b * 8 + 7];
        off[8] = base + s;
      }
    }
  }
  __syncthreads();
  if (tid < 128) {
    const int idx = rb * 128 + tid;
    const int c = cat[idx];
    const int r = atomicAdd(&lcur[c], 1);
    list[starts[c] + r] = idx;
  }
}

// ---------------- front kernel: W_in transpose + histogram + out bias-init ----------------
// [0,128): W_in transpose; [128,192): histogram; [192,448): out[r] = b2[cat[r]]
__global__ __launch_bounds__(256) void wsmall(const float* __restrict__ W_in,
                                              const int* __restrict__ cat,
                                              const float* __restrict__ b2,
                                              u16* __restrict__ o0, int* __restrict__ cnts,
                                              float* __restrict__ out) {
  __shared__ float tbuf[64][65];
  const int bid = blockIdx.x, tid = threadIdx.x;
  if (bid >= 192) {                        // out bias-init: 32 rows/block
    const int r = (bid - 192) * 32 + (tid >> 3);
    const int co = (tid & 7) * 8;
    const int c = cat[r];
    float4 v0 = *reinterpret_cast<const float4*>(b2 + c * 64 + co);
    float4 v1 = *reinterpret_cast<const float4*>(b2 + c * 64 + co + 4);
    *reinterpret_cast<float4*>(out + (size_t)r * 64 + co) = v0;
    *reinterpret_cast<float4*>(out + (size_t)r * 64 + co + 4) = v1;
    return;
  }
  if (bid >= 128) { hist_body(bid - 128, cat, cnts); return; }
  transpose_tile(tbuf, W_in, o0, 512, 1024, bid >> 4, bid & 15, 0);
}

// ---------------- unified GEMM + T1 swizzle (R3 loop) ----------------
// L1: A = x f32 reg-staged; riders y==8 scatter, y==9..16 W1, y==17 W2.
// L2: gathered rows, bf16 h in LDS epilogue, fused L3 PV + atomicAdd into out.

template<int LAYER, int BN, int K, int N>
__global__ __launch_bounds__(256, 4) void gemm_t(
    const float* __restrict__ Xf, const u16* __restrict__ A,
    const u16* __restrict__ Bw, const float* __restrict__ bias,
    const int* __restrict__ list, const int* __restrict__ off,
    u16* __restrict__ outb, float* __restrict__ outf,
    const int* __restrict__ cat, const int* __restrict__ cnts,
    int* __restrict__ wlist, int* __restrict__ woff,
    const float* __restrict__ Wc1, const float* __restrict__ Wc2,
    u16* __restrict__ o1, u16* __restrict__ o2) {
  struct GBuf { alignas(16) u16 As[2][2048]; alignas(16) u16 Bs[2][BN * 32]; };
  __shared__ union SM {
    GBuf g;
    float tbuf[64][65];
    u16 ht[64 * 136];                      // L2 epilogue: h tile (pad 136 for banks+align)
  } sm;

  const int tid = threadIdx.x;

  if constexpr (LAYER == 1) {
    if (blockIdx.y == 8) {
      if (blockIdx.x < 64) scatter_body(blockIdx.x, cat, cnts, wlist, woff);
      return;
    }
    if (blockIdx.y >= 9) {
      if (blockIdx.y <= 16) {
        const int t = (blockIdx.y - 9) * 128 + blockIdx.x;
        const int z = t >> 7, rem = t & 127;
        transpose_tile(sm.tbuf, Wc1, o1, 1024, 512, rem >> 3, rem & 7,
                       (size_t)z * 1024 * 512);
      } else if (blockIdx.x < 64) {
        const int t = blockIdx.x, z = t >> 3;
        transpose_tile(sm.tbuf, Wc2, o2, 512, 64, t & 7, 0, (size_t)z * 512 * 64);
      }
      return;
    }
  }

  // ---- T1: XCD-chunked bijective block swizzle ----
  int tidx, col0;
  if constexpr (LAYER == 1) {
    const int orig = blockIdx.y * 128 + blockIdx.x;
    const int work = (orig & 7) * 128 + (orig >> 3);
    tidx = work >> 3;
    col0 = (work & 7) * BN;
  } else {
    const int orig = blockIdx.y * 136 + blockIdx.x;
    const int work = (orig & 7) * 68 + (orig >> 3);
    tidx = work >> 2;
    col0 = (work & 3) * BN;
  }

  const int wave = tid >> 6, lane = tid & 63;

  int e = 0, start = 0, cnt = 0, rowbase;
  if constexpr (LAYER == 1) {
    rowbase = tidx * 64;
  } else {
    int t = tidx;
    int found = -1;
    for (e = 0; e < 8; e++) {
      int tiles = (off[e + 1] - off[e] + 63) >> 6;
      if (t < tiles) { found = e; break; }
      t -= tiles;
    }
    if (found < 0) return;
    start = off[e];
    cnt = off[e + 1] - start;
    rowbase = t * 64;
  }

  const int srow = tid >> 2, skc = tid & 3;
  const int kxs = (skc ^ (srow & 3)) * 8;

  const float* ax = nullptr;
  const u16* a_src = nullptr;
  if constexpr (LAYER == 1) {
    ax = Xf + (size_t)(rowbase + srow) * K + kxs;
  } else {
    int gr = list[start + min(rowbase + srow, cnt - 1)];
    a_src = A + (size_t)gr * K + kxs;
  }
  const u16* Bbase = Bw + (LAYER == 1 ? (size_t)0 : (size_t)e * N * K);
  const u16* b_src0 = Bbase + (size_t)(col0 + srow) * K + kxs;
  const u16* b_src1 = Bbase + (size_t)(col0 + 64 + srow) * K + kxs;

  const int wbase = wave * 512;

  constexpr int NR = BN / 32;
  const int wy = wave & 1, wx = wave >> 1;
  const int fr = lane & 15, kg = lane >> 4;
  const int kx = (kg ^ (fr & 3)) * 8;
  const int ar0 = (wy * 32 + fr) * 32 + kx;
  const int br0 = (wx * (BN / 2) + fr) * 32 + kx;

  f32x4 acc[2][NR] = {};

  float4 va0, va1;
  auto LOAD_A1 = [&](int t) {
    va0 = *reinterpret_cast<const float4*>(ax + t * 32);
    va1 = *reinterpret_cast<const float4*>(ax + t * 32 + 4);
  };
  auto WRITE_A1 = [&](int buf) {
    uint4 w;
    w.x = (u32)f2b(va0.x) | ((u32)f2b(va0.y) << 16);
    w.y = (u32)f2b(va0.z) | ((u32)f2b(va0.w) << 16);
    w.z = (u32)f2b(va1.x) | ((u32)f2b(va1.y) << 16);
    w.w = (u32)f2b(va1.z) | ((u32)f2b(va1.w) << 16);
    *reinterpret_cast<uint4*>(&sm.g.As[buf][srow * 32 + skc * 8]) = w;
  };
  auto COMPUTE = [&](int buf) {
    bf16x8 af[2], bfv[NR];
#pragma unroll
    for (int m = 0; m < 2; m++) af[m] = *(const bf16x8*)&sm.g.As[buf][ar0 + m * 16 * 32];
#pragma unroll
    for (int n = 0; n < NR; n++) bfv[n] = *(const bf16x8*)&sm.g.Bs[buf][br0 + n * 16 * 32];
#pragma unroll
    for (int m = 0; m < 2; m++)
#pragma unroll
      for (int n = 0; n < NR; n++)
        acc[m][n] = __builtin_amdgcn_mfma_f32_16x16x32_bf16(af[m], bfv[n], acc[m][n], 0, 0, 0);
  };

  constexpr int NK = K / 32;
  if constexpr (LAYER == 1) LOAD_A1(0);
  else GLD_LDS(a_src, &sm.g.As[0][wbase]);
  GLD_LDS(b_src0, &sm.g.Bs[0][wbase]);
  if constexpr (BN == 128) GLD_LDS(b_src1, &sm.g.Bs[0][2048 + wbase]);
  if constexpr (LAYER == 1) WRITE_A1(0);
  __syncthreads();

  for (int it = 0; it < NK; ++it) {
    const int cur = it & 1;
    const int nxt = cur ^ 1;
    if (it + 1 < NK) {
      const int kt = (it + 1) * 32;
      if constexpr (LAYER == 1) LOAD_A1(it + 1);
      else GLD_LDS(a_src + kt, &sm.g.As[nxt][wbase]);
      GLD_LDS(b_src0 + kt, &sm.g.Bs[nxt][wbase]);
      if constexpr (BN == 128) GLD_LDS(b_src1 + kt, &sm.g.Bs[nxt][2048 + wbase]);
    }
    COMPUTE(cur);
    if constexpr (LAYER == 1) { if (it + 1 < NK) WRITE_A1(nxt); }
    __syncthreads();
  }

  if constexpr (LAYER == 1) {
    // epilogue: bf16 out + ELU
#pragma unroll
    for (int n = 0; n < NR; n++) {
      const int col = col0 + wx * (BN / 2) + n * 16 + fr;
      const float bc = bias[col];
#pragma unroll
      for (int m = 0; m < 2; m++) {
        const int rloc = wy * 32 + m * 16 + kg * 4;
#pragma unroll
        for (int j = 0; j < 4; j++)
          outb[(size_t)(rowbase + rloc + j) * N + col] = f2b(elu1(acc[m][n][j] + bc));
      }
    }
  } else {
    // ---- fused L3: h(elu) -> LDS, PV vs W2 slice, atomicAdd partials into out ----
    // (loop's final __syncthreads() already protects LDS reuse)
#pragma unroll
    for (int n = 0; n < NR; n++) {
      const int lcol = wx * 64 + n * 16 + fr;
      const float bc = bias[e * N + col0 + lcol];
#pragma unroll
      for (int m = 0; m < 2; m++) {
        const int rl = wy * 32 + m * 16 + kg * 4;
#pragma unroll
        for (int j = 0; j < 4; j++)
          sm.ht[(rl + j) * 136 + lcol] = f2b(elu1(acc[m][n][j] + bc));
      }
    }
    __syncthreads();

    const u16* w2p = o2 + (size_t)e * 64 * 512 + col0;   // W2[e][ocol][k], k-slice at col0
    f32x4 po[2][2] = {};
#pragma unroll
    for (int ks = 0; ks < 4; ks++) {
      bf16x8 pa[2], pb[2];
#pragma unroll
      for (int m = 0; m < 2; m++)
        pa[m] = *(const bf16x8*)&sm.ht[(wy * 32 + m * 16 + fr) * 136 + ks * 32 + kg * 8];
#pragma unroll
      for (int n = 0; n < 2; n++)
        pb[n] = *(const bf16x8*)&w2p[(size_t)(wx * 32 + n * 16 + fr) * 512 + ks * 32 + kg * 8];
#pragma unroll
      for (int m = 0; m < 2; m++)
#pragma unroll
        for (int n = 0; n < 2; n++)
          po[m][n] = __builtin_amdgcn_mfma_f32_16x16x32_bf16(pa[m], pb[n], po[m][n], 0, 0, 0);
    }
#pragma unroll
    for (int n = 0; n < 2; n++) {
      const int oc = wx * 32 + n * 16 + fr;
#pragma unroll
      for (int m = 0; m < 2; m++) {
        const int sl0 = rowbase + wy * 32 + m * 16 + kg * 4;
#pragma unroll
        for (int j = 0; j < 4; j++) {
          const int slot = sl0 + j;
          if (slot < cnt)
            atomicAdd(&outf[(size_t)list[start + slot] * 64 + oc], po[m][n][j]);
        }
      }
    }
  }
}

// ---------------- launch ----------------

extern "C" void kernel_launch(void* const* d_in, const int* in_sizes, int n_in,
                              void* d_out, int out_size, void* d_ws, size_t ws_size,
                              hipStream_t stream) {
  const float* x    = (const float*)d_in[0];
  const int*   cat  = (const int*)d_in[1];
  const float* W_in = (const float*)d_in[2];
  const float* b_in = (const float*)d_in[3];
  const float* W1   = (const float*)d_in[4];
  const float* b1   = (const float*)d_in[5];
  const float* W2   = (const float*)d_in[6];
  const float* b2   = (const float*)d_in[7];
  float* out = (float*)d_out;

  char* p = (char*)d_ws;
  u16* midb = (u16*)p; p += (size_t)8192 * 1024 * 2;   // 16 MB
  u16* wtin = (u16*)p; p += (size_t)1024 * 512 * 2;    // 1 MB
  u16* w1t  = (u16*)p; p += (size_t)8 * 512 * 1024 * 2;// 8 MB
  u16* w2t  = (u16*)p; p += (size_t)8 * 64 * 512 * 2;  // 0.5 MB
  int* list = (int*)p; p += (size_t)8192 * 4;          // 32 KB
  int* off  = (int*)p; p += 64;
  int* cnts = (int*)p; p += 64 * 8 * 4;

  // D1: W_in transpose + histogram + out bias-init
  wsmall<<<448, 256, 0, stream>>>(W_in, cat, b2, wtin, cnts, out);

  // D2: L1 gemm (x as f32) + scatter (y==8) + W1/W2 converts (y>=9)
  gemm_t<1, 128, 512, 1024><<<dim3(128, 18), 256, 0, stream>>>(
      x, nullptr, wtin, b_in, nullptr, nullptr, midb, nullptr,
      cat, cnts, list, off, W1, W2, w1t, w2t);

  // D3: L2+L3 fused  [cnt_e,1024] @ W1[e] -> h (LDS) -> @ W2[e] -> atomicAdd out
  gemm_t<2, 128, 1024, 512><<<dim3(136, 4), 256, 0, stream>>>(
      nullptr, midb, w1t, b1, list, off, nullptr, out,
      nullptr, nullptr, nullptr, nullptr, nullptr, nullptr, nullptr, w2t);
}